// Round 2
// baseline (282.669 us; speedup 1.0000x reference)
//
#include <hip/hip_runtime.h>
#include <math.h>

// ConvolutionalCapsule EM routing, fused, one block per output position.
// R2 changes vs R1: 1024 threads/block (IPT 9, 16 waves -> 4/SIMD occupancy),
// W double-buffer prefetch, stride-17 padded LDS accumulators (conflict-free),
// fast-math intrinsics for exp/log/rcp.

#define EPSF 1e-7f
#define KKI 288
#define NC 32
#define NTHREADS 1024
#define NSUB 32        // NTHREADS/32
#define IPT 9          // KKI/NSUB

__device__ __forceinline__ float frcp(float x) { return __builtin_amdgcn_rcpf(x); }

__global__ __launch_bounds__(NTHREADS)
void caps_em_kernel(const float* __restrict__ x, const float* __restrict__ Wg,
                    const float* __restrict__ beta_v, const float* __restrict__ beta_a,
                    float* __restrict__ out)
{
    __shared__ float MpL[KKI * 16];   // patch poses
    __shared__ float apL[KKI];        // patch activations
    __shared__ float T1L[NC * 17];    // sum_i Rw*v   (stride 17: conflict-free)
    __shared__ float S1L[NC * 17];    // sum_i v      (iteration-invariant)
    __shared__ float S2L[NC * 17];    // sum_i v^2    (iteration-invariant)
    __shared__ float RsumL[NC];
    __shared__ float ML[NC * 17];     // M
    __shared__ float I2L[NC * 17];    // 1/(2*var)
    __shared__ float constL[NC];      // log(a_j+eps) - sum_d log(stdv+eps)
    __shared__ float aoutL[NC];       // sigmoid(a_j)

    const int t = threadIdx.x;
    const int bid = blockIdx.x;           // b*144 + ho*12 + wo
    const int b = bid / 144;
    const int rem = bid - b * 144;
    const int ho = rem / 12;
    const int wo = rem - ho * 12;

    const int c = t & 31;
    const int isub = t >> 5;

    // ---- stage patch tile ----
    for (int idx = t; idx < KKI * 17; idx += NTHREADS) {
        int i = idx / 17;
        int e = idx - i * 17;
        int p = i >> 5, cin = i & 31;
        int di = p / 3, dj = p - di * 3;
        float vx = x[(((b * 14 + (ho + di)) * 14 + (wo + dj)) * 32 + cin) * 17 + e];
        if (e < 16) MpL[i * 16 + e] = vx; else apL[i] = vx;
    }
    for (int idx = t; idx < NC * 17; idx += NTHREADS) { T1L[idx] = 0.f; S1L[idx] = 0.f; S2L[idx] = 0.f; }
    if (t < NC) RsumL[t] = 0.f;
    __syncthreads();

    // stats phase: wave 0, lanes 0..31, one output capsule per lane
    auto stats = [&](float inv_temp) {
        if (t < NC) {
            int cc = t;
            float rsum = RsumL[cc];
            float inv_rsum = frcp(rsum);
            float bv = beta_v[cc];
            float cost = 0.f, slog = 0.f;
            #pragma unroll
            for (int d = 0; d < 16; ++d) {
                float m = T1L[cc * 17 + d] * inv_rsum;
                float var = S2L[cc * 17 + d] - 2.f * m * S1L[cc * 17 + d] + 288.f * m * m;
                var = fmaxf(var, 0.f);
                float stdv = __fsqrt_rn(var);
                float lg = __logf(stdv + EPSF);
                slog += lg;
                cost += bv + lg;
                ML[cc * 17 + d] = m;
                I2L[cc * 17 + d] = 0.5f * frcp(var);
            }
            cost *= rsum;
            float csum = cost;
            csum += __shfl_xor(csum, 16); csum += __shfl_xor(csum, 8);
            csum += __shfl_xor(csum, 4);  csum += __shfl_xor(csum, 2);
            csum += __shfl_xor(csum, 1);
            float c_mean = csum * 0.03125f;
            float diff = cost - c_mean;
            float dsq = diff * diff;
            dsq += __shfl_xor(dsq, 16); dsq += __shfl_xor(dsq, 8);
            dsq += __shfl_xor(dsq, 4);  dsq += __shfl_xor(dsq, 2);
            dsq += __shfl_xor(dsq, 1);
            float c_stdv = __fsqrt_rn(dsq * 0.03125f);
            float a_cost = beta_a[cc] + (c_mean - cost) * frcp(c_stdv + EPSF);
            float a_j = frcp(1.f + __expf(-inv_temp * a_cost));
            constL[cc] = __logf(a_j + EPSF) - slog;
            aoutL[cc] = frcp(1.f + __expf(-a_j));
        }
    };

    const float* wbase = Wg + (size_t)((isub * IPT) * NC + c) * 16;

    // ---- pass 0: R uniform 1/32; also build S1,S2 ----
    {
        float t1[16], s1[16], s2[16];
        #pragma unroll
        for (int d = 0; d < 16; ++d) { t1[d] = 0.f; s1[d] = 0.f; s2[d] = 0.f; }
        float rsum = 0.f;
        // prefetch j=0 W row
        float4 w0, w1, w2, w3;
        {
            const float4* wp = (const float4*)wbase;
            w0 = wp[0]; w1 = wp[1]; w2 = wp[2]; w3 = wp[3];
        }
        for (int j = 0; j < IPT; ++j) {
            int i = isub * IPT + j;
            float a_i = apL[i];
            // prefetch next W row while computing this one
            int jn = (j + 1 < IPT) ? j + 1 : j;
            const float4* wpn = (const float4*)(wbase + (size_t)jn * NC * 16);
            float4 nw0 = wpn[0], nw1 = wpn[1], nw2 = wpn[2], nw3 = wpn[3];

            float wa[16], ma[16];
            ((float4*)wa)[0] = w0; ((float4*)wa)[1] = w1;
            ((float4*)wa)[2] = w2; ((float4*)wa)[3] = w3;
            const float4* mp4 = (const float4*)(MpL + i * 16);
            ((float4*)ma)[0] = mp4[0]; ((float4*)ma)[1] = mp4[1];
            ((float4*)ma)[2] = mp4[2]; ((float4*)ma)[3] = mp4[3];
            float v[16];
            #pragma unroll
            for (int p = 0; p < 4; ++p)
                #pragma unroll
                for (int r = 0; r < 4; ++r) {
                    float acc = ma[p * 4 + 0] * wa[0 * 4 + r];
                    acc = fmaf(ma[p * 4 + 1], wa[1 * 4 + r], acc);
                    acc = fmaf(ma[p * 4 + 2], wa[2 * 4 + r], acc);
                    acc = fmaf(ma[p * 4 + 3], wa[3 * 4 + r], acc);
                    v[p * 4 + r] = acc;
                }
            float rw = a_i * 0.03125f;
            rsum += rw;
            #pragma unroll
            for (int d = 0; d < 16; ++d) {
                t1[d] = fmaf(rw, v[d], t1[d]);
                s1[d] += v[d];
                s2[d] = fmaf(v[d], v[d], s2[d]);
            }
            w0 = nw0; w1 = nw1; w2 = nw2; w3 = nw3;
        }
        rsum += __shfl_xor(rsum, 32);
        #pragma unroll
        for (int d = 0; d < 16; ++d) {
            t1[d] += __shfl_xor(t1[d], 32);
            s1[d] += __shfl_xor(s1[d], 32);
            s2[d] += __shfl_xor(s2[d], 32);
        }
        if ((t & 32) == 0) {
            atomicAdd(&RsumL[c], rsum);
            #pragma unroll
            for (int d = 0; d < 16; ++d) {
                atomicAdd(&T1L[c * 17 + d], t1[d]);
                atomicAdd(&S1L[c * 17 + d], s1[d]);
                atomicAdd(&S2L[c * 17 + d], s2[d]);
            }
        }
        __syncthreads();
        stats(1.0f);   // it = 0
        __syncthreads();
    }

    // ---- passes 1,2: fused E-step (in-register softmax over c) + M-step ----
    for (int it = 1; it < 3; ++it) {
        float Mreg[16], i2[16];
        #pragma unroll
        for (int d = 0; d < 16; ++d) { Mreg[d] = ML[c * 17 + d]; i2[d] = I2L[c * 17 + d]; }
        float Kc = constL[c];
        for (int idx = t; idx < NC * 17; idx += NTHREADS) T1L[idx] = 0.f;
        if (t < NC) RsumL[t] = 0.f;
        __syncthreads();

        float t1[16];
        #pragma unroll
        for (int d = 0; d < 16; ++d) t1[d] = 0.f;
        float rsum = 0.f;
        float4 w0, w1, w2, w3;
        {
            const float4* wp = (const float4*)wbase;
            w0 = wp[0]; w1 = wp[1]; w2 = wp[2]; w3 = wp[3];
        }
        for (int j = 0; j < IPT; ++j) {
            int i = isub * IPT + j;
            float a_i = apL[i];
            int jn = (j + 1 < IPT) ? j + 1 : j;
            const float4* wpn = (const float4*)(wbase + (size_t)jn * NC * 16);
            float4 nw0 = wpn[0], nw1 = wpn[1], nw2 = wpn[2], nw3 = wpn[3];

            float wa[16], ma[16];
            ((float4*)wa)[0] = w0; ((float4*)wa)[1] = w1;
            ((float4*)wa)[2] = w2; ((float4*)wa)[3] = w3;
            const float4* mp4 = (const float4*)(MpL + i * 16);
            ((float4*)ma)[0] = mp4[0]; ((float4*)ma)[1] = mp4[1];
            ((float4*)ma)[2] = mp4[2]; ((float4*)ma)[3] = mp4[3];
            float v[16];
            #pragma unroll
            for (int p = 0; p < 4; ++p)
                #pragma unroll
                for (int r = 0; r < 4; ++r) {
                    float acc = ma[p * 4 + 0] * wa[0 * 4 + r];
                    acc = fmaf(ma[p * 4 + 1], wa[1 * 4 + r], acc);
                    acc = fmaf(ma[p * 4 + 2], wa[2 * 4 + r], acc);
                    acc = fmaf(ma[p * 4 + 3], wa[3 * 4 + r], acc);
                    v[p * 4 + r] = acc;
                }
            float lp = Kc;
            #pragma unroll
            for (int d = 0; d < 16; ++d) {
                float df = v[d] - Mreg[d];
                lp = fmaf(-df * df, i2[d], lp);
            }
            // softmax over the 32 caps held by this half-wave
            float mx = lp;
            mx = fmaxf(mx, __shfl_xor(mx, 16)); mx = fmaxf(mx, __shfl_xor(mx, 8));
            mx = fmaxf(mx, __shfl_xor(mx, 4));  mx = fmaxf(mx, __shfl_xor(mx, 2));
            mx = fmaxf(mx, __shfl_xor(mx, 1));
            float ex = __expf(lp - mx);
            float s = ex;
            s += __shfl_xor(s, 16); s += __shfl_xor(s, 8);
            s += __shfl_xor(s, 4);  s += __shfl_xor(s, 2);
            s += __shfl_xor(s, 1);
            float r = ex * frcp(s);
            float rw = r * a_i;
            rsum += rw;
            #pragma unroll
            for (int d = 0; d < 16; ++d) t1[d] = fmaf(rw, v[d], t1[d]);
            w0 = nw0; w1 = nw1; w2 = nw2; w3 = nw3;
        }
        rsum += __shfl_xor(rsum, 32);
        #pragma unroll
        for (int d = 0; d < 16; ++d) t1[d] += __shfl_xor(t1[d], 32);
        if ((t & 32) == 0) {
            atomicAdd(&RsumL[c], rsum);
            #pragma unroll
            for (int d = 0; d < 16; ++d) atomicAdd(&T1L[c * 17 + d], t1[d]);
        }
        __syncthreads();
        stats(1.0f + (float)it);   // inv_temp = 1 + it
        __syncthreads();
    }

    // ---- epilogue ----
    for (int idx = t; idx < NC * 17; idx += NTHREADS) {
        int cc = idx / 17;
        int e = idx - cc * 17;
        float val = (e < 16) ? ML[cc * 17 + e] : aoutL[cc];
        out[(size_t)bid * (NC * 17) + idx] = val;
    }
}

extern "C" void kernel_launch(void* const* d_in, const int* in_sizes, int n_in,
                              void* d_out, int out_size, void* d_ws, size_t ws_size,
                              hipStream_t stream) {
    const float* x  = (const float*)d_in[0];
    const float* W  = (const float*)d_in[1];
    const float* bv = (const float*)d_in[2];
    const float* ba = (const float*)d_in[3];
    float* out = (float*)d_out;
    caps_em_kernel<<<288, NTHREADS, 0, stream>>>(x, W, bv, ba, out);
}

// Round 3
// 254.000 us; speedup vs baseline: 1.1129x; 1.1129x over previous
//
#include <hip/hip_runtime.h>
#include <math.h>

// ConvolutionalCapsule EM routing, fused, one block per output position.
// R3 vs R2: __launch_bounds__(1024,4) -> VGPR cap 128 (R2 capped at 64 and
// spilled 74MB to scratch); register-trimmed inner loops; stats phase
// parallelized over 512 (cap,dim) threads instead of 32 lanes serial-16.

#define EPSF 1e-7f
#define KKI 288
#define NC 32
#define NTHREADS 1024
#define NSUB 32        // NTHREADS/32
#define IPT 9          // KKI/NSUB

__device__ __forceinline__ float frcp(float x) { return __builtin_amdgcn_rcpf(x); }

__global__ __launch_bounds__(NTHREADS, 4)
void caps_em_kernel(const float* __restrict__ x, const float* __restrict__ Wg,
                    const float* __restrict__ beta_v, const float* __restrict__ beta_a,
                    float* __restrict__ out)
{
    __shared__ float MpL[KKI * 16];   // patch poses
    __shared__ float apL[KKI];        // patch activations
    __shared__ float T1L[NC * 17];    // sum_i Rw*v   (stride 17: conflict-free)
    __shared__ float S1L[NC * 17];    // sum_i v      (iteration-invariant)
    __shared__ float S2L[NC * 17];    // sum_i v^2    (iteration-invariant)
    __shared__ float RsumL[NC];
    __shared__ float ML[NC * 17];     // M
    __shared__ float I2L[NC * 17];    // 1/(2*var)
    __shared__ float constL[NC];      // log(a_j+eps) - sum_d log(stdv+eps)
    __shared__ float aoutL[NC];       // sigmoid(a_j)
    __shared__ float costL[NC];       // per-cap cost (stats intermediate)
    __shared__ float slogL[NC];       // per-cap sum log(stdv+eps)

    const int t = threadIdx.x;
    const int bid = blockIdx.x;           // b*144 + ho*12 + wo
    const int b = bid / 144;
    const int rem = bid - b * 144;
    const int ho = rem / 12;
    const int wo = rem - ho * 12;

    const int c = t & 31;
    const int isub = t >> 5;

    // ---- stage patch tile ----
    for (int idx = t; idx < KKI * 17; idx += NTHREADS) {
        int i = idx / 17;
        int e = idx - i * 17;
        int p = i >> 5, cin = i & 31;
        int di = p / 3, dj = p - di * 3;
        float vx = x[(((b * 14 + (ho + di)) * 14 + (wo + dj)) * 32 + cin) * 17 + e];
        if (e < 16) MpL[i * 16 + e] = vx; else apL[i] = vx;
    }
    for (int idx = t; idx < NC * 17; idx += NTHREADS) { T1L[idx] = 0.f; S1L[idx] = 0.f; S2L[idx] = 0.f; }
    if (t < NC) RsumL[t] = 0.f;
    __syncthreads();

    // stats phase, two parts with a barrier between (caller provides barriers).
    // part A: 512 threads, one (cap cc, dim dd) each: m, var, stdv, log; then
    // shuffle-reduce over the 16-lane d-group to get per-cap cost & slog.
    auto statsA = [&]() {
        if (t < NC * 16) {
            int cc = t >> 4, dd = t & 15;
            float rsum = RsumL[cc];
            float inv_rsum = frcp(rsum);
            float m = T1L[cc * 17 + dd] * inv_rsum;
            float var = S2L[cc * 17 + dd] - 2.f * m * S1L[cc * 17 + dd] + 288.f * m * m;
            var = fmaxf(var, 0.f);
            float stdv = __fsqrt_rn(var);
            float lg = __logf(stdv + EPSF);
            ML[cc * 17 + dd] = m;
            I2L[cc * 17 + dd] = 0.5f * frcp(var);
            float ch = beta_v[cc] + lg;          // cost_h element (pre *rsum)
            float sl = lg;
            ch += __shfl_xor(ch, 8); sl += __shfl_xor(sl, 8);
            ch += __shfl_xor(ch, 4); sl += __shfl_xor(sl, 4);
            ch += __shfl_xor(ch, 2); sl += __shfl_xor(sl, 2);
            ch += __shfl_xor(ch, 1); sl += __shfl_xor(sl, 1);
            if (dd == 0) { costL[cc] = ch * rsum; slogL[cc] = sl; }
        }
    };
    // part B: 32 lanes, cross-cap mean/stdv -> a_j, constL, aoutL.
    auto statsB = [&](float inv_temp) {
        if (t < NC) {
            int cc = t;
            float cost = costL[cc];
            float csum = cost;
            csum += __shfl_xor(csum, 16); csum += __shfl_xor(csum, 8);
            csum += __shfl_xor(csum, 4);  csum += __shfl_xor(csum, 2);
            csum += __shfl_xor(csum, 1);
            float c_mean = csum * 0.03125f;
            float diff = cost - c_mean;
            float dsq = diff * diff;
            dsq += __shfl_xor(dsq, 16); dsq += __shfl_xor(dsq, 8);
            dsq += __shfl_xor(dsq, 4);  dsq += __shfl_xor(dsq, 2);
            dsq += __shfl_xor(dsq, 1);
            float c_stdv = __fsqrt_rn(dsq * 0.03125f);
            float a_cost = beta_a[cc] + (c_mean - cost) * frcp(c_stdv + EPSF);
            float a_j = frcp(1.f + __expf(-inv_temp * a_cost));
            constL[cc] = __logf(a_j + EPSF) - slogL[cc];
            aoutL[cc] = frcp(1.f + __expf(-a_j));
        }
    };

    const float* wbase = Wg + (size_t)((isub * IPT) * NC + c) * 16;

    // ---- pass 0: R uniform 1/32; build T1 (= S1a/32), S1, S2 ----
    {
        float t1[16], s1[16], s2[16];
        #pragma unroll
        for (int d = 0; d < 16; ++d) { t1[d] = 0.f; s1[d] = 0.f; s2[d] = 0.f; }
        float rsum = 0.f;
        float4 w0, w1, w2, w3;
        {
            const float4* wp = (const float4*)wbase;
            w0 = wp[0]; w1 = wp[1]; w2 = wp[2]; w3 = wp[3];
        }
        for (int j = 0; j < IPT; ++j) {
            int i = isub * IPT + j;
            float a_i = apL[i];
            int jn = (j + 1 < IPT) ? j + 1 : j;
            const float4* wpn = (const float4*)(wbase + (size_t)jn * NC * 16);
            float4 nw0 = wpn[0], nw1 = wpn[1], nw2 = wpn[2], nw3 = wpn[3];

            float wa[16];
            ((float4*)wa)[0] = w0; ((float4*)wa)[1] = w1;
            ((float4*)wa)[2] = w2; ((float4*)wa)[3] = w3;
            const float4* mp4 = (const float4*)(MpL + i * 16);
            float rw = a_i * 0.03125f;
            rsum += rw;
            #pragma unroll
            for (int p = 0; p < 4; ++p) {
                float4 mp = mp4[p];
                #pragma unroll
                for (int r = 0; r < 4; ++r) {
                    float v = mp.x * wa[0 * 4 + r];
                    v = fmaf(mp.y, wa[1 * 4 + r], v);
                    v = fmaf(mp.z, wa[2 * 4 + r], v);
                    v = fmaf(mp.w, wa[3 * 4 + r], v);
                    int d = p * 4 + r;
                    t1[d] = fmaf(rw, v, t1[d]);
                    s1[d] += v;
                    s2[d] = fmaf(v, v, s2[d]);
                }
            }
            w0 = nw0; w1 = nw1; w2 = nw2; w3 = nw3;
        }
        rsum += __shfl_xor(rsum, 32);
        #pragma unroll
        for (int d = 0; d < 16; ++d) {
            t1[d] += __shfl_xor(t1[d], 32);
            s1[d] += __shfl_xor(s1[d], 32);
            s2[d] += __shfl_xor(s2[d], 32);
        }
        if ((t & 32) == 0) {
            atomicAdd(&RsumL[c], rsum);
            #pragma unroll
            for (int d = 0; d < 16; ++d) {
                atomicAdd(&T1L[c * 17 + d], t1[d]);
                atomicAdd(&S1L[c * 17 + d], s1[d]);
                atomicAdd(&S2L[c * 17 + d], s2[d]);
            }
        }
        __syncthreads();
        statsA();
        __syncthreads();
        statsB(1.0f);   // it = 0
        __syncthreads();
    }

    // ---- passes 1,2: fused E-step (in-register softmax over c) + M-step ----
    for (int it = 1; it < 3; ++it) {
        float Mreg[16], i2[16];
        #pragma unroll
        for (int d = 0; d < 16; ++d) { Mreg[d] = ML[c * 17 + d]; i2[d] = I2L[c * 17 + d]; }
        float Kc = constL[c];
        for (int idx = t; idx < NC * 17; idx += NTHREADS) T1L[idx] = 0.f;
        if (t < NC) RsumL[t] = 0.f;
        __syncthreads();

        float t1[16];
        #pragma unroll
        for (int d = 0; d < 16; ++d) t1[d] = 0.f;
        float rsum = 0.f;
        float4 w0, w1, w2, w3;
        {
            const float4* wp = (const float4*)wbase;
            w0 = wp[0]; w1 = wp[1]; w2 = wp[2]; w3 = wp[3];
        }
        for (int j = 0; j < IPT; ++j) {
            int i = isub * IPT + j;
            float a_i = apL[i];
            int jn = (j + 1 < IPT) ? j + 1 : j;
            const float4* wpn = (const float4*)(wbase + (size_t)jn * NC * 16);
            float4 nw0 = wpn[0], nw1 = wpn[1], nw2 = wpn[2], nw3 = wpn[3];

            float wa[16];
            ((float4*)wa)[0] = w0; ((float4*)wa)[1] = w1;
            ((float4*)wa)[2] = w2; ((float4*)wa)[3] = w3;
            const float4* mp4 = (const float4*)(MpL + i * 16);
            float v[16];
            #pragma unroll
            for (int p = 0; p < 4; ++p) {
                float4 mp = mp4[p];
                #pragma unroll
                for (int r = 0; r < 4; ++r) {
                    float acc = mp.x * wa[0 * 4 + r];
                    acc = fmaf(mp.y, wa[1 * 4 + r], acc);
                    acc = fmaf(mp.z, wa[2 * 4 + r], acc);
                    acc = fmaf(mp.w, wa[3 * 4 + r], acc);
                    v[p * 4 + r] = acc;
                }
            }
            float lp = Kc;
            #pragma unroll
            for (int d = 0; d < 16; ++d) {
                float df = v[d] - Mreg[d];
                lp = fmaf(-df * df, i2[d], lp);
            }
            // softmax over the 32 caps held by this half-wave
            float mx = lp;
            mx = fmaxf(mx, __shfl_xor(mx, 16)); mx = fmaxf(mx, __shfl_xor(mx, 8));
            mx = fmaxf(mx, __shfl_xor(mx, 4));  mx = fmaxf(mx, __shfl_xor(mx, 2));
            mx = fmaxf(mx, __shfl_xor(mx, 1));
            float ex = __expf(lp - mx);
            float s = ex;
            s += __shfl_xor(s, 16); s += __shfl_xor(s, 8);
            s += __shfl_xor(s, 4);  s += __shfl_xor(s, 2);
            s += __shfl_xor(s, 1);
            float r = ex * frcp(s);
            float rw = r * a_i;
            rsum += rw;
            #pragma unroll
            for (int d = 0; d < 16; ++d) t1[d] = fmaf(rw, v[d], t1[d]);
            w0 = nw0; w1 = nw1; w2 = nw2; w3 = nw3;
        }
        rsum += __shfl_xor(rsum, 32);
        #pragma unroll
        for (int d = 0; d < 16; ++d) t1[d] += __shfl_xor(t1[d], 32);
        if ((t & 32) == 0) {
            atomicAdd(&RsumL[c], rsum);
            #pragma unroll
            for (int d = 0; d < 16; ++d) atomicAdd(&T1L[c * 17 + d], t1[d]);
        }
        __syncthreads();
        statsA();
        __syncthreads();
        statsB(1.0f + (float)it);   // inv_temp = 1 + it
        __syncthreads();
    }

    // ---- epilogue ----
    for (int idx = t; idx < NC * 17; idx += NTHREADS) {
        int cc = idx / 17;
        int e = idx - cc * 17;
        float val = (e < 16) ? ML[cc * 17 + e] : aoutL[cc];
        out[(size_t)bid * (NC * 17) + idx] = val;
    }
}

extern "C" void kernel_launch(void* const* d_in, const int* in_sizes, int n_in,
                              void* d_out, int out_size, void* d_ws, size_t ws_size,
                              hipStream_t stream) {
    const float* x  = (const float*)d_in[0];
    const float* W  = (const float*)d_in[1];
    const float* bv = (const float*)d_in[2];
    const float* ba = (const float*)d_in[3];
    float* out = (float*)d_out;
    caps_em_kernel<<<288, NTHREADS, 0, stream>>>(x, W, bv, ba, out);
}

// Round 4
// 252.183 us; speedup vs baseline: 1.1209x; 1.0072x over previous
//
#include <hip/hip_runtime.h>
#include <math.h>

// ConvolutionalCapsule EM routing, fused, one block per output position.
// R4 vs R3: __launch_bounds__(1024, 1). Empirics: (1024) and (1024,4) both
// produced a 64-VGPR cap (=> 47MB scratch spill traffic); 64 = 512/8 waves/EU,
// i.e. the 2nd arg behaved as CUDA-style min-BLOCKS/CU. With 1 block/CU the
// cap is 128 under either semantics, fitting the ~110-reg working set.

#define EPSF 1e-7f
#define KKI 288
#define NC 32
#define NTHREADS 1024
#define NSUB 32        // NTHREADS/32
#define IPT 9          // KKI/NSUB

__device__ __forceinline__ float frcp(float x) { return __builtin_amdgcn_rcpf(x); }

__global__ __launch_bounds__(NTHREADS, 1)
void caps_em_kernel(const float* __restrict__ x, const float* __restrict__ Wg,
                    const float* __restrict__ beta_v, const float* __restrict__ beta_a,
                    float* __restrict__ out)
{
    __shared__ float MpL[KKI * 16];   // patch poses
    __shared__ float apL[KKI];        // patch activations
    __shared__ float T1L[NC * 17];    // sum_i Rw*v   (stride 17: conflict-free)
    __shared__ float S1L[NC * 17];    // sum_i v      (iteration-invariant)
    __shared__ float S2L[NC * 17];    // sum_i v^2    (iteration-invariant)
    __shared__ float RsumL[NC];
    __shared__ float ML[NC * 17];     // M
    __shared__ float I2L[NC * 17];    // 1/(2*var)
    __shared__ float constL[NC];      // log(a_j+eps) - sum_d log(stdv+eps)
    __shared__ float aoutL[NC];       // sigmoid(a_j)
    __shared__ float costL[NC];       // per-cap cost (stats intermediate)
    __shared__ float slogL[NC];       // per-cap sum log(stdv+eps)

    const int t = threadIdx.x;
    const int bid = blockIdx.x;           // b*144 + ho*12 + wo
    const int b = bid / 144;
    const int rem = bid - b * 144;
    const int ho = rem / 12;
    const int wo = rem - ho * 12;

    const int c = t & 31;
    const int isub = t >> 5;

    // ---- stage patch tile ----
    for (int idx = t; idx < KKI * 17; idx += NTHREADS) {
        int i = idx / 17;
        int e = idx - i * 17;
        int p = i >> 5, cin = i & 31;
        int di = p / 3, dj = p - di * 3;
        float vx = x[(((b * 14 + (ho + di)) * 14 + (wo + dj)) * 32 + cin) * 17 + e];
        if (e < 16) MpL[i * 16 + e] = vx; else apL[i] = vx;
    }
    for (int idx = t; idx < NC * 17; idx += NTHREADS) { T1L[idx] = 0.f; S1L[idx] = 0.f; S2L[idx] = 0.f; }
    if (t < NC) RsumL[t] = 0.f;
    __syncthreads();

    // stats part A: 512 threads, one (cap cc, dim dd) each; d-group shuffle
    // reduce to per-cap cost & slog.
    auto statsA = [&]() {
        if (t < NC * 16) {
            int cc = t >> 4, dd = t & 15;
            float rsum = RsumL[cc];
            float inv_rsum = frcp(rsum);
            float m = T1L[cc * 17 + dd] * inv_rsum;
            float var = S2L[cc * 17 + dd] - 2.f * m * S1L[cc * 17 + dd] + 288.f * m * m;
            var = fmaxf(var, 0.f);
            float stdv = __fsqrt_rn(var);
            float lg = __logf(stdv + EPSF);
            ML[cc * 17 + dd] = m;
            I2L[cc * 17 + dd] = 0.5f * frcp(var);
            float ch = beta_v[cc] + lg;          // cost_h element (pre *rsum)
            float sl = lg;
            ch += __shfl_xor(ch, 8); sl += __shfl_xor(sl, 8);
            ch += __shfl_xor(ch, 4); sl += __shfl_xor(sl, 4);
            ch += __shfl_xor(ch, 2); sl += __shfl_xor(sl, 2);
            ch += __shfl_xor(ch, 1); sl += __shfl_xor(sl, 1);
            if (dd == 0) { costL[cc] = ch * rsum; slogL[cc] = sl; }
        }
    };
    // stats part B: 32 lanes, cross-cap mean/stdv -> a_j, constL, aoutL.
    auto statsB = [&](float inv_temp) {
        if (t < NC) {
            int cc = t;
            float cost = costL[cc];
            float csum = cost;
            csum += __shfl_xor(csum, 16); csum += __shfl_xor(csum, 8);
            csum += __shfl_xor(csum, 4);  csum += __shfl_xor(csum, 2);
            csum += __shfl_xor(csum, 1);
            float c_mean = csum * 0.03125f;
            float diff = cost - c_mean;
            float dsq = diff * diff;
            dsq += __shfl_xor(dsq, 16); dsq += __shfl_xor(dsq, 8);
            dsq += __shfl_xor(dsq, 4);  dsq += __shfl_xor(dsq, 2);
            dsq += __shfl_xor(dsq, 1);
            float c_stdv = __fsqrt_rn(dsq * 0.03125f);
            float a_cost = beta_a[cc] + (c_mean - cost) * frcp(c_stdv + EPSF);
            float a_j = frcp(1.f + __expf(-inv_temp * a_cost));
            constL[cc] = __logf(a_j + EPSF) - slogL[cc];
            aoutL[cc] = frcp(1.f + __expf(-a_j));
        }
    };

    const float* wbase = Wg + (size_t)((isub * IPT) * NC + c) * 16;

    // ---- pass 0: R uniform 1/32; build T1 (= weighted), S1, S2 ----
    {
        float t1[16], s1[16], s2[16];
        #pragma unroll
        for (int d = 0; d < 16; ++d) { t1[d] = 0.f; s1[d] = 0.f; s2[d] = 0.f; }
        float rsum = 0.f;
        float4 w0, w1, w2, w3;
        {
            const float4* wp = (const float4*)wbase;
            w0 = wp[0]; w1 = wp[1]; w2 = wp[2]; w3 = wp[3];
        }
        for (int j = 0; j < IPT; ++j) {
            int i = isub * IPT + j;
            float a_i = apL[i];
            int jn = (j + 1 < IPT) ? j + 1 : j;
            const float4* wpn = (const float4*)(wbase + (size_t)jn * NC * 16);
            float4 nw0 = wpn[0], nw1 = wpn[1], nw2 = wpn[2], nw3 = wpn[3];

            float wa[16];
            ((float4*)wa)[0] = w0; ((float4*)wa)[1] = w1;
            ((float4*)wa)[2] = w2; ((float4*)wa)[3] = w3;
            const float4* mp4 = (const float4*)(MpL + i * 16);
            float rw = a_i * 0.03125f;
            rsum += rw;
            #pragma unroll
            for (int p = 0; p < 4; ++p) {
                float4 mp = mp4[p];
                #pragma unroll
                for (int r = 0; r < 4; ++r) {
                    float v = mp.x * wa[0 * 4 + r];
                    v = fmaf(mp.y, wa[1 * 4 + r], v);
                    v = fmaf(mp.z, wa[2 * 4 + r], v);
                    v = fmaf(mp.w, wa[3 * 4 + r], v);
                    int d = p * 4 + r;
                    t1[d] = fmaf(rw, v, t1[d]);
                    s1[d] += v;
                    s2[d] = fmaf(v, v, s2[d]);
                }
            }
            w0 = nw0; w1 = nw1; w2 = nw2; w3 = nw3;
        }
        rsum += __shfl_xor(rsum, 32);
        #pragma unroll
        for (int d = 0; d < 16; ++d) {
            t1[d] += __shfl_xor(t1[d], 32);
            s1[d] += __shfl_xor(s1[d], 32);
            s2[d] += __shfl_xor(s2[d], 32);
        }
        if ((t & 32) == 0) {
            atomicAdd(&RsumL[c], rsum);
            #pragma unroll
            for (int d = 0; d < 16; ++d) {
                atomicAdd(&T1L[c * 17 + d], t1[d]);
                atomicAdd(&S1L[c * 17 + d], s1[d]);
                atomicAdd(&S2L[c * 17 + d], s2[d]);
            }
        }
        __syncthreads();
        statsA();
        __syncthreads();
        statsB(1.0f);   // it = 0
        __syncthreads();
    }

    // ---- passes 1,2: fused E-step (in-register softmax over c) + M-step ----
    for (int it = 1; it < 3; ++it) {
        float Mreg[16], i2[16];
        #pragma unroll
        for (int d = 0; d < 16; ++d) { Mreg[d] = ML[c * 17 + d]; i2[d] = I2L[c * 17 + d]; }
        float Kc = constL[c];
        for (int idx = t; idx < NC * 17; idx += NTHREADS) T1L[idx] = 0.f;
        if (t < NC) RsumL[t] = 0.f;
        __syncthreads();

        float t1[16];
        #pragma unroll
        for (int d = 0; d < 16; ++d) t1[d] = 0.f;
        float rsum = 0.f;
        float4 w0, w1, w2, w3;
        {
            const float4* wp = (const float4*)wbase;
            w0 = wp[0]; w1 = wp[1]; w2 = wp[2]; w3 = wp[3];
        }
        for (int j = 0; j < IPT; ++j) {
            int i = isub * IPT + j;
            float a_i = apL[i];
            int jn = (j + 1 < IPT) ? j + 1 : j;
            const float4* wpn = (const float4*)(wbase + (size_t)jn * NC * 16);
            float4 nw0 = wpn[0], nw1 = wpn[1], nw2 = wpn[2], nw3 = wpn[3];

            float wa[16];
            ((float4*)wa)[0] = w0; ((float4*)wa)[1] = w1;
            ((float4*)wa)[2] = w2; ((float4*)wa)[3] = w3;
            const float4* mp4 = (const float4*)(MpL + i * 16);
            float v[16];
            #pragma unroll
            for (int p = 0; p < 4; ++p) {
                float4 mp = mp4[p];
                #pragma unroll
                for (int r = 0; r < 4; ++r) {
                    float acc = mp.x * wa[0 * 4 + r];
                    acc = fmaf(mp.y, wa[1 * 4 + r], acc);
                    acc = fmaf(mp.z, wa[2 * 4 + r], acc);
                    acc = fmaf(mp.w, wa[3 * 4 + r], acc);
                    v[p * 4 + r] = acc;
                }
            }
            float lp = Kc;
            #pragma unroll
            for (int d = 0; d < 16; ++d) {
                float df = v[d] - Mreg[d];
                lp = fmaf(-df * df, i2[d], lp);
            }
            // softmax over the 32 caps held by this half-wave
            float mx = lp;
            mx = fmaxf(mx, __shfl_xor(mx, 16)); mx = fmaxf(mx, __shfl_xor(mx, 8));
            mx = fmaxf(mx, __shfl_xor(mx, 4));  mx = fmaxf(mx, __shfl_xor(mx, 2));
            mx = fmaxf(mx, __shfl_xor(mx, 1));
            float ex = __expf(lp - mx);
            float s = ex;
            s += __shfl_xor(s, 16); s += __shfl_xor(s, 8);
            s += __shfl_xor(s, 4);  s += __shfl_xor(s, 2);
            s += __shfl_xor(s, 1);
            float r = ex * frcp(s);
            float rw = r * a_i;
            rsum += rw;
            #pragma unroll
            for (int d = 0; d < 16; ++d) t1[d] = fmaf(rw, v[d], t1[d]);
            w0 = nw0; w1 = nw1; w2 = nw2; w3 = nw3;
        }
        rsum += __shfl_xor(rsum, 32);
        #pragma unroll
        for (int d = 0; d < 16; ++d) t1[d] += __shfl_xor(t1[d], 32);
        if ((t & 32) == 0) {
            atomicAdd(&RsumL[c], rsum);
            #pragma unroll
            for (int d = 0; d < 16; ++d) atomicAdd(&T1L[c * 17 + d], t1[d]);
        }
        __syncthreads();
        statsA();
        __syncthreads();
        statsB(1.0f + (float)it);   // inv_temp = 1 + it
        __syncthreads();
    }

    // ---- epilogue ----
    for (int idx = t; idx < NC * 17; idx += NTHREADS) {
        int cc = idx / 17;
        int e = idx - cc * 17;
        float val = (e < 16) ? ML[cc * 17 + e] : aoutL[cc];
        out[(size_t)bid * (NC * 17) + idx] = val;
    }
}

extern "C" void kernel_launch(void* const* d_in, const int* in_sizes, int n_in,
                              void* d_out, int out_size, void* d_ws, size_t ws_size,
                              hipStream_t stream) {
    const float* x  = (const float*)d_in[0];
    const float* W  = (const float*)d_in[1];
    const float* bv = (const float*)d_in[2];
    const float* ba = (const float*)d_in[3];
    float* out = (float*)d_out;
    caps_em_kernel<<<288, NTHREADS, 0, stream>>>(x, W, bv, ba, out);
}